// Round 1
// baseline (322.363 us; speedup 1.0000x reference)
//
#include <hip/hip_runtime.h>
#include <math.h>

#define LN_EPS 1e-5f

// ---------------------------------------------------------------------------
// Tiled fp32 GEMM: C[M x N] = op(A[M x K] @ B[K x N] (+bias))
// BM=64, BN=64, BK=16, 256 threads, 4x4 microtile per thread.
// Requires M%64==0, N%64==0, K%16==0 (all shapes here satisfy this).
// ---------------------------------------------------------------------------
template <bool BIAS, bool RELU>
__global__ __launch_bounds__(256) void gemm_kernel(
    const float* __restrict__ A, const float* __restrict__ B,
    const float* __restrict__ bias, float* __restrict__ C,
    int M, int N, int K)
{
    constexpr int BM = 64, BN = 64, BK = 16;
    __shared__ float As[BK][BM];   // [kk][m]
    __shared__ float Bs[BK][BN];   // [kk][n]

    const int tid  = threadIdx.x;
    const int brow = blockIdx.y * BM;
    const int bcol = blockIdx.x * BN;
    const int trow = (tid / 16) * 4;
    const int tcol = (tid % 16) * 4;

    float acc[4][4] = {};

    // per-thread load coordinates (1024 floats per tile / 256 thr = 4 each)
    const int a_r  = tid / 4;            // row in A tile
    const int a_kk = (tid * 4) % BK;     // k offset (0,4,8,12)
    const int b_kk = tid / 16;           // k row in B tile
    const int b_c  = (tid * 4) % BN;     // col offset

    for (int k0 = 0; k0 < K; k0 += BK) {
        // A tile (transposed store into As[kk][m])
        {
            const float* src = A + (size_t)(brow + a_r) * K + k0 + a_kk;
            float4 v = *(const float4*)src;
            As[a_kk + 0][a_r] = v.x;
            As[a_kk + 1][a_r] = v.y;
            As[a_kk + 2][a_r] = v.z;
            As[a_kk + 3][a_r] = v.w;
        }
        // B tile (direct store)
        {
            const float* src = B + (size_t)(k0 + b_kk) * N + bcol + b_c;
            *(float4*)&Bs[b_kk][b_c] = *(const float4*)src;
        }
        __syncthreads();

        #pragma unroll
        for (int kk = 0; kk < BK; ++kk) {
            float4 av = *(const float4*)&As[kk][trow];
            float4 bv = *(const float4*)&Bs[kk][tcol];
            float a[4] = {av.x, av.y, av.z, av.w};
            float b[4] = {bv.x, bv.y, bv.z, bv.w};
            #pragma unroll
            for (int i = 0; i < 4; ++i)
                #pragma unroll
                for (int j = 0; j < 4; ++j)
                    acc[i][j] = fmaf(a[i], b[j], acc[i][j]);
        }
        __syncthreads();
    }

    float bv[4] = {0.f, 0.f, 0.f, 0.f};
    if (BIAS) {
        float4 t = *(const float4*)&bias[bcol + tcol];
        bv[0] = t.x; bv[1] = t.y; bv[2] = t.z; bv[3] = t.w;
    }
    #pragma unroll
    for (int i = 0; i < 4; ++i) {
        float4 o;
        float v0 = acc[i][0] + bv[0];
        float v1 = acc[i][1] + bv[1];
        float v2 = acc[i][2] + bv[2];
        float v3 = acc[i][3] + bv[3];
        if (RELU) {
            v0 = fmaxf(v0, 0.f); v1 = fmaxf(v1, 0.f);
            v2 = fmaxf(v2, 0.f); v3 = fmaxf(v3, 0.f);
        }
        o.x = v0; o.y = v1; o.z = v2; o.w = v3;
        *(float4*)&C[(size_t)(brow + trow + i) * N + bcol + tcol] = o;
    }
}

// ---------------------------------------------------------------------------
// In-place LayerNorm over last dim D=512. One block (256 thr) per row.
// ---------------------------------------------------------------------------
__global__ __launch_bounds__(256) void ln_kernel(
    float* __restrict__ x, const float* __restrict__ g,
    const float* __restrict__ beta)
{
    const int row = blockIdx.x;
    const int tid = threadIdx.x;
    float* p = x + (size_t)row * 512;

    float2 v = *(float2*)&p[tid * 2];
    float s  = v.x + v.y;
    float ss = v.x * v.x + v.y * v.y;

    #pragma unroll
    for (int off = 32; off; off >>= 1) {
        s  += __shfl_down(s, off);
        ss += __shfl_down(ss, off);
    }
    __shared__ float red[8];
    if ((tid & 63) == 0) { red[(tid >> 6) * 2] = s; red[(tid >> 6) * 2 + 1] = ss; }
    __syncthreads();
    __shared__ float stats[2];
    if (tid == 0) {
        float S = red[0] + red[2] + red[4] + red[6];
        float SS = red[1] + red[3] + red[5] + red[7];
        float mu  = S * (1.f / 512.f);
        float var = SS * (1.f / 512.f) - mu * mu;
        stats[0] = mu;
        stats[1] = rsqrtf(var + LN_EPS);
    }
    __syncthreads();
    const float mu = stats[0], rstd = stats[1];
    float2 gv = *(const float2*)&g[tid * 2];
    float2 bv = *(const float2*)&beta[tid * 2];
    v.x = (v.x - mu) * rstd * gv.x + bv.x;
    v.y = (v.y - mu) * rstd * gv.y + bv.y;
    *(float2*)&p[tid * 2] = v;
}

// ---------------------------------------------------------------------------
// scores[b,e,r] = sigmoid( sum_d relu(h_t[b,e,d] + h_i[b,r,d]) * W2[d] + b2 )
// One block per (b,e); each of 4 waves handles r = wave, wave+4, ...
// ---------------------------------------------------------------------------
__global__ __launch_bounds__(256) void scores_kernel(
    const float* __restrict__ ht,   // [B*E][512]
    const float* __restrict__ hi,   // [B][36][512]
    const float* __restrict__ W2,   // [512]
    const float* __restrict__ b2,   // [1]
    float* __restrict__ scores)     // [B*E][36]
{
    const int be   = blockIdx.x;     // b*64 + e
    const int b    = be >> 6;
    const int tid  = threadIdx.x;
    const int lane = tid & 63;
    const int wave = tid >> 6;

    float htv[8], w2v[8];
    const float* htp = ht + (size_t)be * 512;
    #pragma unroll
    for (int j = 0; j < 8; ++j) {
        htv[j] = htp[lane + 64 * j];
        w2v[j] = W2[lane + 64 * j];
    }
    const float bb = b2[0];
    const float* hib = hi + (size_t)b * 36 * 512;

    for (int r = wave; r < 36; r += 4) {
        const float* hir = hib + (size_t)r * 512;
        float acc = 0.f;
        #pragma unroll
        for (int j = 0; j < 8; ++j) {
            float h = fmaxf(htv[j] + hir[lane + 64 * j], 0.f);
            acc = fmaf(h, w2v[j], acc);
        }
        #pragma unroll
        for (int off = 32; off; off >>= 1) acc += __shfl_down(acc, off);
        if (lane == 0) {
            float sr = acc + bb;
            scores[(size_t)be * 36 + r] = 1.f / (1.f + expf(-sr));
        }
    }
}

// ---------------------------------------------------------------------------
// Per-batch softmax over 64*36 scores, then
// aggregated[b,d] = sum_r (sum_e w[b,e,r]) * img[b,r,d] / 64
// One block (256 thr) per batch.
// ---------------------------------------------------------------------------
__global__ __launch_bounds__(256) void agg_kernel(
    const float* __restrict__ scores,  // [B][64*36]
    const float* __restrict__ img,     // [B][36][512]
    float* __restrict__ outAgg)        // [B][512]
{
    const int b   = blockIdx.x;
    const int tid = threadIdx.x;
    const float* sc = scores + (size_t)b * 2304;

    // denom = sum of exp(score) (scores are in (0,1); no max-shift needed)
    float local = 0.f;
    for (int i = tid; i < 2304; i += 256) local += expf(sc[i]);
    #pragma unroll
    for (int off = 32; off; off >>= 1) local += __shfl_down(local, off);
    __shared__ float red[4];
    if ((tid & 63) == 0) red[tid >> 6] = local;
    __syncthreads();
    __shared__ float denom_s;
    if (tid == 0) denom_s = red[0] + red[1] + red[2] + red[3];
    __syncthreads();
    const float inv = 1.f / (denom_s * 64.f);   // includes the /E factor

    __shared__ float wsr[36];
    if (tid < 36) {
        float s = 0.f;
        for (int e = 0; e < 64; ++e) s += expf(sc[e * 36 + tid]);
        wsr[tid] = s * inv;
    }
    __syncthreads();

    const float* ib = img + (size_t)b * 36 * 512;
    for (int d = tid; d < 512; d += 256) {
        float acc = 0.f;
        #pragma unroll
        for (int r = 0; r < 36; ++r) acc = fmaf(wsr[r], ib[r * 512 + d], acc);
        outAgg[(size_t)b * 512 + d] = acc;
    }
}

// ---------------------------------------------------------------------------
extern "C" void kernel_launch(void* const* d_in, const int* in_sizes, int n_in,
                              void* d_out, int out_size, void* d_ws, size_t ws_size,
                              hipStream_t stream)
{
    const float* text      = (const float*)d_in[0];   // [32,64,768]
    const float* image     = (const float*)d_in[1];   // [32,36,2048]
    const float* W_text    = (const float*)d_in[2];   // [768,512]
    const float* b_text    = (const float*)d_in[3];
    const float* g_text    = (const float*)d_in[4];
    const float* beta_text = (const float*)d_in[5];
    const float* W_img     = (const float*)d_in[6];   // [2048,512]
    const float* b_img     = (const float*)d_in[7];
    const float* g_img     = (const float*)d_in[8];
    const float* beta_img  = (const float*)d_in[9];
    const float* W1        = (const float*)d_in[10];  // [1024,512]
    const float* b1        = (const float*)d_in[11];
    const float* W2        = (const float*)d_in[12];  // [512,1]
    const float* b2        = (const float*)d_in[13];

    float* out_scores = (float*)d_out;            // 32*64*36 = 73728
    float* out_agg    = (float*)d_out + 73728;    // 32*512   = 16384

    float* ws = (float*)d_ws;
    float* ta = ws;                    // 2048*512  text proj -> aligned (in-place LN)
    float* ia = ta + 2048 * 512;       // 1152*512  image proj -> aligned
    float* ht = ia + 1152 * 512;       // 2048*512
    float* hi = ht + 2048 * 512;       // 1152*512

    // 1) text projection + bias + relu   [2048 x 768] @ [768 x 512]
    gemm_kernel<true, true><<<dim3(8, 32), 256, 0, stream>>>(
        text, W_text, b_text, ta, 2048, 512, 768);
    // 2) image projection + bias + relu  [1152 x 2048] @ [2048 x 512]
    gemm_kernel<true, true><<<dim3(8, 18), 256, 0, stream>>>(
        image, W_img, b_img, ia, 1152, 512, 2048);
    // 3) LayerNorms (in place)
    ln_kernel<<<2048, 256, 0, stream>>>(ta, g_text, beta_text);
    ln_kernel<<<1152, 256, 0, stream>>>(ia, g_img, beta_img);
    // 4) h_t = text_aligned @ W1[:512]         (no bias)
    gemm_kernel<false, false><<<dim3(8, 32), 256, 0, stream>>>(
        ta, W1, nullptr, ht, 2048, 512, 512);
    // 5) h_i = image_aligned @ W1[512:] + b1
    gemm_kernel<true, false><<<dim3(8, 18), 256, 0, stream>>>(
        ia, W1 + 512 * 512, b1, hi, 1152, 512, 512);
    // 6) pair scores + sigmoid -> out[0]
    scores_kernel<<<2048, 256, 0, stream>>>(ht, hi, W2, b2, out_scores);
    // 7) softmax + aggregation -> out[1]
    agg_kernel<<<32, 256, 0, stream>>>(out_scores, ia, out_agg);
}

// Round 2
// 171.486 us; speedup vs baseline: 1.8798x; 1.8798x over previous
//
#include <hip/hip_runtime.h>
#include <math.h>

#define LN_EPS 1e-5f

typedef __attribute__((ext_vector_type(8))) short bf16x8;
typedef __attribute__((ext_vector_type(4))) float f32x4;
typedef unsigned short ushort_t;
typedef unsigned int uint_t;

__device__ __forceinline__ ushort_t f2bf(float f) {
    uint_t u = __float_as_uint(f);
    u += 0x7FFF + ((u >> 16) & 1);          // RNE
    return (ushort_t)(u >> 16);
}

// ---------------------------------------------------------------------------
// Convert text + image activations fp32 -> bf16 (flat, 4 elems/thread).
// total = 2048*768 + 1152*2048 = 3,932,160 elems = 3840 blocks * 256 * 4.
// ---------------------------------------------------------------------------
__global__ __launch_bounds__(256) void convert_ab_kernel(
    const float* __restrict__ text, const float* __restrict__ image,
    ushort_t* __restrict__ text_bf, ushort_t* __restrict__ image_bf)
{
    const int i4 = (blockIdx.x * 256 + threadIdx.x) * 4;
    const float* src;
    ushort_t* dst;
    int off;
    if (i4 < 1572864) { src = text;  dst = text_bf;  off = i4; }
    else              { src = image; dst = image_bf; off = i4 - 1572864; }
    float4 v = *(const float4*)(src + off);
    ushort4 o;
    o.x = f2bf(v.x); o.y = f2bf(v.y); o.z = f2bf(v.z); o.w = f2bf(v.w);
    *(ushort4*)(dst + off) = o;
}

// ---------------------------------------------------------------------------
// Transpose-convert weights: src fp32 [K][512] -> dst bf16 [512][K].
// 32x32 tiles, 256 threads (32x8). Four segments hardcoded.
// ---------------------------------------------------------------------------
__global__ __launch_bounds__(256) void transpose_w_kernel(
    const float* __restrict__ W_text, const float* __restrict__ W_img,
    const float* __restrict__ W1,
    ushort_t* __restrict__ Wt_t, ushort_t* __restrict__ Wi_t,
    ushort_t* __restrict__ W1t_t, ushort_t* __restrict__ W1i_t)
{
    __shared__ float t[32][33];
    int bid = blockIdx.x;
    const float* src; ushort_t* dst; int K, local;
    if      (bid < 384)  { src = W_text;          dst = Wt_t;  K = 768;  local = bid; }
    else if (bid < 1408) { src = W_img;           dst = Wi_t;  K = 2048; local = bid - 384; }
    else if (bid < 1664) { src = W1;              dst = W1t_t; K = 512;  local = bid - 1408; }
    else                 { src = W1 + 512 * 512;  dst = W1i_t; K = 512;  local = bid - 1664; }
    const int ntk = K / 32;
    const int k0 = (local % ntk) * 32;
    const int n0 = (local / ntk) * 32;
    const int x = threadIdx.x % 32, y = threadIdx.x / 32;
    #pragma unroll
    for (int j = 0; j < 4; ++j)
        t[y + 8 * j][x] = src[(size_t)(k0 + y + 8 * j) * 512 + n0 + x];
    __syncthreads();
    #pragma unroll
    for (int j = 0; j < 4; ++j)
        dst[(size_t)(n0 + y + 8 * j) * K + k0 + x] = f2bf(t[x][y + 8 * j]);
}

// ---------------------------------------------------------------------------
// bf16 MFMA GEMM: C[M x N] fp32 = A[M x K]bf16 @ B, with B given as
// Bt[N x K]bf16 (both operands K-contiguous). Optional +bias, relu.
// Block tile 64x64, BK=32, 4 waves each 32x32 (2x2 of 16x16x32 mfma).
// Register-prefetch pipeline on the global->LDS staging.
// ---------------------------------------------------------------------------
template <bool BIAS, bool RELU>
__global__ __launch_bounds__(256) void gemm_bf16_kernel(
    const ushort_t* __restrict__ A, const ushort_t* __restrict__ Bt,
    const float* __restrict__ bias, float* __restrict__ C,
    int M, int N, int K)
{
    __shared__ ushort_t Al[4][64][8];   // [k-quad][m][j]  4 KB
    __shared__ ushort_t Bl[4][64][8];   // [k-quad][n][j]  4 KB

    const int tid  = threadIdx.x;
    const int brow = blockIdx.y * 64;
    const int bcol = blockIdx.x * 64;
    const int wave = tid >> 6;
    const int lane = tid & 63;
    const int q    = lane >> 4;         // mfma quad
    const int mj   = lane & 15;

    // staging: thread -> (row sm, k-quad skq); 16 B per thread per tile
    const int sm  = tid >> 2;
    const int skq = tid & 3;
    const ushort_t* Ap = A  + (size_t)(brow + sm) * K + skq * 8;
    const ushort_t* Bp = Bt + (size_t)(bcol + sm) * K + skq * 8;

    const int wr = (wave >> 1) * 32;    // wave row offset
    const int wc = (wave & 1) * 32;     // wave col offset

    f32x4 acc[2][2] = {};

    int4 areg = *(const int4*)Ap;
    int4 breg = *(const int4*)Bp;

    for (int k0 = 0; k0 < K; k0 += 32) {
        __syncthreads();                // LDS free from previous iter's reads
        *(int4*)&Al[skq][sm][0] = areg;
        *(int4*)&Bl[skq][sm][0] = breg;
        __syncthreads();
        if (k0 + 32 < K) {              // prefetch next tile (overlaps mfma)
            areg = *(const int4*)(Ap + k0 + 32);
            breg = *(const int4*)(Bp + k0 + 32);
        }
        bf16x8 af[2], bf[2];
        af[0] = *(bf16x8*)&Al[q][wr + mj][0];
        af[1] = *(bf16x8*)&Al[q][wr + 16 + mj][0];
        bf[0] = *(bf16x8*)&Bl[q][wc + mj][0];
        bf[1] = *(bf16x8*)&Bl[q][wc + 16 + mj][0];
        #pragma unroll
        for (int mi = 0; mi < 2; ++mi)
            #pragma unroll
            for (int ni = 0; ni < 2; ++ni)
                acc[mi][ni] = __builtin_amdgcn_mfma_f32_16x16x32_bf16(
                    af[mi], bf[ni], acc[mi][ni], 0, 0, 0);
    }

    // epilogue: C/D layout col=lane&15, row=quad*4+reg
    #pragma unroll
    for (int mi = 0; mi < 2; ++mi) {
        const int rbase = brow + wr + mi * 16 + q * 4;
        #pragma unroll
        for (int ni = 0; ni < 2; ++ni) {
            const int col = bcol + wc + ni * 16 + mj;
            const float bv = BIAS ? bias[col] : 0.f;
            #pragma unroll
            for (int r = 0; r < 4; ++r) {
                float v = acc[mi][ni][r] + bv;
                if (RELU) v = fmaxf(v, 0.f);
                C[(size_t)(rbase + r) * N + col] = v;
            }
        }
    }
}

// ---------------------------------------------------------------------------
// LayerNorm over D=512: read fp32, write bf16 (always) + fp32 (optional).
// One block (256 thr) per row.
// ---------------------------------------------------------------------------
template <bool FP_OUT>
__global__ __launch_bounds__(256) void ln_kernel(
    const float* __restrict__ x, const float* __restrict__ g,
    const float* __restrict__ beta, ushort_t* __restrict__ out_bf,
    float* __restrict__ out_fp)
{
    const int row = blockIdx.x;
    const int tid = threadIdx.x;
    const float* p = x + (size_t)row * 512;

    float2 v = *(const float2*)&p[tid * 2];
    float s  = v.x + v.y;
    float ss = v.x * v.x + v.y * v.y;

    #pragma unroll
    for (int off = 32; off; off >>= 1) {
        s  += __shfl_down(s, off);
        ss += __shfl_down(ss, off);
    }
    __shared__ float red[8];
    if ((tid & 63) == 0) { red[(tid >> 6) * 2] = s; red[(tid >> 6) * 2 + 1] = ss; }
    __syncthreads();
    __shared__ float stats[2];
    if (tid == 0) {
        float S  = red[0] + red[2] + red[4] + red[6];
        float SS = red[1] + red[3] + red[5] + red[7];
        float mu  = S * (1.f / 512.f);
        float var = SS * (1.f / 512.f) - mu * mu;
        stats[0] = mu;
        stats[1] = rsqrtf(var + LN_EPS);
    }
    __syncthreads();
    const float mu = stats[0], rstd = stats[1];
    float2 gv = *(const float2*)&g[tid * 2];
    float2 bv = *(const float2*)&beta[tid * 2];
    float o0 = (v.x - mu) * rstd * gv.x + bv.x;
    float o1 = (v.y - mu) * rstd * gv.y + bv.y;
    ushort2 ob; ob.x = f2bf(o0); ob.y = f2bf(o1);
    *(ushort2*)&out_bf[(size_t)row * 512 + tid * 2] = ob;
    if (FP_OUT) {
        float2 of; of.x = o0; of.y = o1;
        *(float2*)&out_fp[(size_t)row * 512 + tid * 2] = of;
    }
}

// ---------------------------------------------------------------------------
// scores[b,e,r] = sigmoid( sum_d relu(h_t[b,e,d] + h_i[b,r,d]) * W2[d] + b2 )
// One block per (b,e); wave w handles r = w, w+4, ...
// ---------------------------------------------------------------------------
__global__ __launch_bounds__(256) void scores_kernel(
    const float* __restrict__ ht, const float* __restrict__ hi,
    const float* __restrict__ W2, const float* __restrict__ b2,
    float* __restrict__ scores)
{
    const int be   = blockIdx.x;
    const int b    = be >> 6;
    const int tid  = threadIdx.x;
    const int lane = tid & 63;
    const int wave = tid >> 6;

    float htv[8], w2v[8];
    const float* htp = ht + (size_t)be * 512;
    #pragma unroll
    for (int j = 0; j < 8; ++j) {
        htv[j] = htp[lane + 64 * j];
        w2v[j] = W2[lane + 64 * j];
    }
    const float bb = b2[0];
    const float* hib = hi + (size_t)b * 36 * 512;

    for (int r = wave; r < 36; r += 4) {
        const float* hir = hib + (size_t)r * 512;
        float acc = 0.f;
        #pragma unroll
        for (int j = 0; j < 8; ++j) {
            float h = fmaxf(htv[j] + hir[lane + 64 * j], 0.f);
            acc = fmaf(h, w2v[j], acc);
        }
        #pragma unroll
        for (int off = 32; off; off >>= 1) acc += __shfl_down(acc, off);
        if (lane == 0) {
            float sr = acc + bb;
            scores[(size_t)be * 36 + r] = 1.f / (1.f + expf(-sr));
        }
    }
}

// ---------------------------------------------------------------------------
// Per-batch softmax over 64*36 scores, then
// aggregated[b,d] = sum_r (sum_e w[b,e,r]) * img[b,r,d] / 64
// ---------------------------------------------------------------------------
__global__ __launch_bounds__(256) void agg_kernel(
    const float* __restrict__ scores, const float* __restrict__ img,
    float* __restrict__ outAgg)
{
    const int b   = blockIdx.x;
    const int tid = threadIdx.x;
    const float* sc = scores + (size_t)b * 2304;

    float local = 0.f;
    for (int i = tid; i < 2304; i += 256) local += expf(sc[i]);
    #pragma unroll
    for (int off = 32; off; off >>= 1) local += __shfl_down(local, off);
    __shared__ float red[4];
    if ((tid & 63) == 0) red[tid >> 6] = local;
    __syncthreads();
    __shared__ float denom_s;
    if (tid == 0) denom_s = red[0] + red[1] + red[2] + red[3];
    __syncthreads();
    const float inv = 1.f / (denom_s * 64.f);

    __shared__ float wsr[36];
    if (tid < 36) {
        float s = 0.f;
        for (int e = 0; e < 64; ++e) s += expf(sc[e * 36 + tid]);
        wsr[tid] = s * inv;
    }
    __syncthreads();

    const float* ib = img + (size_t)b * 36 * 512;
    for (int d = tid; d < 512; d += 256) {
        float acc = 0.f;
        #pragma unroll
        for (int r = 0; r < 36; ++r) acc = fmaf(wsr[r], ib[r * 512 + d], acc);
        outAgg[(size_t)b * 512 + d] = acc;
    }
}

// ---------------------------------------------------------------------------
extern "C" void kernel_launch(void* const* d_in, const int* in_sizes, int n_in,
                              void* d_out, int out_size, void* d_ws, size_t ws_size,
                              hipStream_t stream)
{
    const float* text      = (const float*)d_in[0];   // [32,64,768]
    const float* image     = (const float*)d_in[1];   // [32,36,2048]
    const float* W_text    = (const float*)d_in[2];   // [768,512]
    const float* b_text    = (const float*)d_in[3];
    const float* g_text    = (const float*)d_in[4];
    const float* beta_text = (const float*)d_in[5];
    const float* W_img     = (const float*)d_in[6];   // [2048,512]
    const float* b_img     = (const float*)d_in[7];
    const float* g_img     = (const float*)d_in[8];
    const float* beta_img  = (const float*)d_in[9];
    const float* W1        = (const float*)d_in[10];  // [1024,512]
    const float* b1        = (const float*)d_in[11];
    const float* W2        = (const float*)d_in[12];  // [512,1]
    const float* b2        = (const float*)d_in[13];

    float* out_scores = (float*)d_out;            // 32*64*36
    float* out_agg    = (float*)d_out + 73728;    // 32*512

    // workspace layout (bytes), all 16B aligned; ht/hi alias the dead
    // text_bf/image_bf region:
    char* ws = (char*)d_ws;
    float*    ta       = (float*)(ws);                          // 4 MB
    float*    ia       = (float*)(ws + (4u << 20));             // 2.25 MB
    ushort_t* text_bf  = (ushort_t*)(ws + 6402048);             // 3 MB   } region X
    ushort_t* image_bf = (ushort_t*)(ws + 6402048 + 3145728);   // 4.5 MB } 7.5 MB
    float*    ht       = (float*)(ws + 6402048);                // 4 MB   (aliases X)
    float*    hi       = (float*)(ws + 6402048 + 4194304);      // 2.25 MB(aliases X)
    char*     wbase    = ws + 6402048 + 7864320;
    ushort_t* Wt_t     = (ushort_t*)(wbase);                    // 512*768*2  = 0.75 MB
    ushort_t* Wi_t     = (ushort_t*)(wbase + 786432);           // 512*2048*2 = 2 MB
    ushort_t* W1t_t    = (ushort_t*)(wbase + 786432 + 2097152); // 0.5 MB
    ushort_t* W1i_t    = (ushort_t*)(wbase + 786432 + 2097152 + 524288);
    char*     bfbase   = wbase + 786432 + 2097152 + 2 * 524288;
    ushort_t* ta_bf    = (ushort_t*)(bfbase);                   // 2 MB
    ushort_t* ia_bf    = (ushort_t*)(bfbase + 2097152);         // 1.125 MB

    // 1) activations fp32 -> bf16
    convert_ab_kernel<<<3840, 256, 0, stream>>>(text, image, text_bf, image_bf);
    // 2) weights fp32 [K][512] -> bf16 [512][K]
    transpose_w_kernel<<<1920, 256, 0, stream>>>(W_text, W_img, W1,
                                                 Wt_t, Wi_t, W1t_t, W1i_t);
    // 3) text projection + bias + relu
    gemm_bf16_kernel<true, true><<<dim3(8, 32), 256, 0, stream>>>(
        text_bf, Wt_t, b_text, ta, 2048, 512, 768);
    // 4) image projection + bias + relu
    gemm_bf16_kernel<true, true><<<dim3(8, 18), 256, 0, stream>>>(
        image_bf, Wi_t, b_img, ia, 1152, 512, 2048);
    // 5) LayerNorms: text -> bf16 only; image -> bf16 + fp32 (in place)
    ln_kernel<false><<<2048, 256, 0, stream>>>(ta, g_text, beta_text, ta_bf, nullptr);
    ln_kernel<true><<<1152, 256, 0, stream>>>(ia, g_img, beta_img, ia_bf, ia);
    // 6) h_t = text_aligned @ W1[:512]
    gemm_bf16_kernel<false, false><<<dim3(8, 32), 256, 0, stream>>>(
        ta_bf, W1t_t, nullptr, ht, 2048, 512, 512);
    // 7) h_i = image_aligned @ W1[512:] + b1
    gemm_bf16_kernel<true, false><<<dim3(8, 18), 256, 0, stream>>>(
        ia_bf, W1i_t, b1, hi, 1152, 512, 512);
    // 8) pair scores + sigmoid -> out[0]
    scores_kernel<<<2048, 256, 0, stream>>>(ht, hi, W2, b2, out_scores);
    // 9) softmax + aggregation -> out[1]
    agg_kernel<<<32, 256, 0, stream>>>(out_scores, ia, out_agg);
}

// Round 3
// 148.006 us; speedup vs baseline: 2.1780x; 1.1586x over previous
//
#include <hip/hip_runtime.h>
#include <math.h>

#define LN_EPS 1e-5f

typedef __attribute__((ext_vector_type(8))) short bf16x8;
typedef __attribute__((ext_vector_type(4))) float f32x4;
typedef unsigned short ushort_t;
typedef unsigned int uint_t;

__device__ __forceinline__ ushort_t f2bf(float f) {
    uint_t u = __float_as_uint(f);
    u += 0x7FFF + ((u >> 16) & 1);          // RNE
    return (ushort_t)(u >> 16);
}

// ---------------------------------------------------------------------------
// Prep: blocks [0,3840) convert activations fp32->bf16 (flat, 4 elems/thr);
//       blocks [3840,5760) transpose-convert weights [K][512]f32 -> [512][K]bf16.
// ---------------------------------------------------------------------------
__global__ __launch_bounds__(256) void prep_kernel(
    const float* __restrict__ text, const float* __restrict__ image,
    ushort_t* __restrict__ text_bf, ushort_t* __restrict__ image_bf,
    const float* __restrict__ W_text, const float* __restrict__ W_img,
    const float* __restrict__ W1,
    ushort_t* __restrict__ Wt_t, ushort_t* __restrict__ Wi_t,
    ushort_t* __restrict__ W1t_t, ushort_t* __restrict__ W1i_t)
{
    __shared__ float t[32][33];
    const int bid = blockIdx.x;
    if (bid < 3840) {
        const int i4 = (bid * 256 + threadIdx.x) * 4;
        const float* src; ushort_t* dst; int off;
        if (i4 < 1572864) { src = text;  dst = text_bf;  off = i4; }
        else              { src = image; dst = image_bf; off = i4 - 1572864; }
        float4 v = *(const float4*)(src + off);
        ushort4 o;
        o.x = f2bf(v.x); o.y = f2bf(v.y); o.z = f2bf(v.z); o.w = f2bf(v.w);
        *(ushort4*)(dst + off) = o;
        return;
    }
    int local = bid - 3840;
    const float* src; ushort_t* dst; int K;
    if      (local < 384)  { src = W_text;         dst = Wt_t;  K = 768;  }
    else if (local < 1408) { src = W_img;          dst = Wi_t;  K = 2048; local -= 384; }
    else if (local < 1664) { src = W1;             dst = W1t_t; K = 512;  local -= 1408; }
    else                   { src = W1 + 512 * 512; dst = W1i_t; K = 512;  local -= 1664; }
    const int ntk = K / 32;
    const int k0 = (local % ntk) * 32;
    const int n0 = (local / ntk) * 32;
    const int x = threadIdx.x % 32, y = threadIdx.x / 32;
    #pragma unroll
    for (int j = 0; j < 4; ++j)
        t[y + 8 * j][x] = src[(size_t)(k0 + y + 8 * j) * 512 + n0 + x];
    __syncthreads();
    #pragma unroll
    for (int j = 0; j < 4; ++j)
        dst[(size_t)(n0 + y + 8 * j) * K + k0 + x] = f2bf(t[x][y + 8 * j]);
}

// ---------------------------------------------------------------------------
// Barrier-free split-K bf16 MFMA GEMM. C[64 x 64] per block, N = 512 fixed.
// Both operands K-contiguous bf16 (A[M][K], Bt[N][K]). 4 waves split K into
// 4 chunks; MFMA fragments loaded DIRECTLY from global (16 B per lane, the
// exact 16x16x32 A/B layout: row=lane&15, k=(lane>>4)*8+j). No LDS, no
// __syncthreads in the K-loop; one LDS reduction + bias/relu epilogue.
// Two problems per launch, selected by blockIdx.y (y < ysplit -> problem 0).
// ---------------------------------------------------------------------------
__global__ __launch_bounds__(256) void gemm_splitk_kernel(
    const ushort_t* __restrict__ A0, const ushort_t* __restrict__ B0,
    const float* __restrict__ bias0, float* __restrict__ C0, int K0,
    const ushort_t* __restrict__ A1, const ushort_t* __restrict__ B1,
    const float* __restrict__ bias1, float* __restrict__ C1, int K1,
    int ysplit, int relu)
{
    __shared__ float red[4][64][64];    // 64 KB

    const ushort_t* A; const ushort_t* Bt; const float* bias; float* C; int K;
    int yy = blockIdx.y;
    if (yy < ysplit) { A = A0; Bt = B0; bias = bias0; C = C0; K = K0; }
    else { A = A1; Bt = B1; bias = bias1; C = C1; K = K1; yy -= ysplit; }

    const int tid  = threadIdx.x;
    const int wave = tid >> 6;
    const int lane = tid & 63;
    const int q    = lane >> 4;
    const int mj   = lane & 15;
    const int brow = yy * 64;
    const int bcol = blockIdx.x * 64;

    const ushort_t* Ab = A  + (size_t)(brow + mj) * K + q * 8;
    const ushort_t* Bb = Bt + (size_t)(bcol + mj) * K + q * 8;
    const int kw0    = wave * (K >> 2);
    const int ksteps = K >> 7;          // (K/4)/32 per wave

    f32x4 acc[4][4] = {};

    #pragma unroll 2
    for (int s = 0; s < ksteps; ++s) {
        const int k = kw0 + s * 32;
        bf16x8 af[4], bf[4];
        #pragma unroll
        for (int i = 0; i < 4; ++i) {
            af[i] = *(const bf16x8*)(Ab + (size_t)i * 16 * K + k);
            bf[i] = *(const bf16x8*)(Bb + (size_t)i * 16 * K + k);
        }
        #pragma unroll
        for (int mi = 0; mi < 4; ++mi)
            #pragma unroll
            for (int ni = 0; ni < 4; ++ni)
                acc[mi][ni] = __builtin_amdgcn_mfma_f32_16x16x32_bf16(
                    af[mi], bf[ni], acc[mi][ni], 0, 0, 0);
    }

    // partials -> LDS  (C/D layout: row=q*4+r, col=mj within each 16x16)
    #pragma unroll
    for (int mi = 0; mi < 4; ++mi)
        #pragma unroll
        for (int ni = 0; ni < 4; ++ni)
            #pragma unroll
            for (int r = 0; r < 4; ++r)
                red[wave][mi * 16 + q * 4 + r][ni * 16 + mj] = acc[mi][ni][r];
    __syncthreads();

    // 4-way sum + bias/relu + store; 16 outputs per thread as 4x float4
    #pragma unroll
    for (int g = 0; g < 4; ++g) {
        const int idx = g * 1024 + tid * 4;
        const int row = idx >> 6, col = idx & 63;
        float4 v0 = *(float4*)&red[0][row][col];
        float4 v1 = *(float4*)&red[1][row][col];
        float4 v2 = *(float4*)&red[2][row][col];
        float4 v3 = *(float4*)&red[3][row][col];
        float4 o;
        o.x = (v0.x + v1.x) + (v2.x + v3.x);
        o.y = (v0.y + v1.y) + (v2.y + v3.y);
        o.z = (v0.z + v1.z) + (v2.z + v3.z);
        o.w = (v0.w + v1.w) + (v2.w + v3.w);
        if (bias) {
            float4 bv = *(const float4*)&bias[bcol + col];
            o.x += bv.x; o.y += bv.y; o.z += bv.z; o.w += bv.w;
        }
        if (relu) {
            o.x = fmaxf(o.x, 0.f); o.y = fmaxf(o.y, 0.f);
            o.z = fmaxf(o.z, 0.f); o.w = fmaxf(o.w, 0.f);
        }
        *(float4*)&C[(size_t)(brow + row) * 512 + bcol + col] = o;
    }
}

// ---------------------------------------------------------------------------
// Fused LayerNorm over D=512 for both matrices. rows [0,2048) = text
// (bf16 out only); rows [2048,3200) = image (bf16 + fp32 in-place).
// ---------------------------------------------------------------------------
__global__ __launch_bounds__(256) void ln_fused_kernel(
    float* __restrict__ ta, const float* __restrict__ g_t,
    const float* __restrict__ be_t, ushort_t* __restrict__ ta_bf,
    float* __restrict__ ia, const float* __restrict__ g_i,
    const float* __restrict__ be_i, ushort_t* __restrict__ ia_bf)
{
    const int tid = threadIdx.x;
    int row = blockIdx.x;
    float* p; const float* g; const float* beta; ushort_t* obf; float* ofp;
    if (row < 2048) {
        p = ta + (size_t)row * 512; g = g_t; beta = be_t;
        obf = ta_bf + (size_t)row * 512; ofp = nullptr;
    } else {
        row -= 2048;
        p = ia + (size_t)row * 512; g = g_i; beta = be_i;
        obf = ia_bf + (size_t)row * 512; ofp = p;
    }

    float2 v = *(const float2*)&p[tid * 2];
    float s  = v.x + v.y;
    float ss = v.x * v.x + v.y * v.y;
    #pragma unroll
    for (int off = 32; off; off >>= 1) {
        s  += __shfl_down(s, off);
        ss += __shfl_down(ss, off);
    }
    __shared__ float red[8];
    if ((tid & 63) == 0) { red[(tid >> 6) * 2] = s; red[(tid >> 6) * 2 + 1] = ss; }
    __syncthreads();
    __shared__ float stats[2];
    if (tid == 0) {
        float S  = red[0] + red[2] + red[4] + red[6];
        float SS = red[1] + red[3] + red[5] + red[7];
        float mu  = S * (1.f / 512.f);
        float var = SS * (1.f / 512.f) - mu * mu;
        stats[0] = mu;
        stats[1] = rsqrtf(var + LN_EPS);
    }
    __syncthreads();
    const float mu = stats[0], rstd = stats[1];
    float2 gv = *(const float2*)&g[tid * 2];
    float2 bv = *(const float2*)&beta[tid * 2];
    float o0 = (v.x - mu) * rstd * gv.x + bv.x;
    float o1 = (v.y - mu) * rstd * gv.y + bv.y;
    ushort2 ob; ob.x = f2bf(o0); ob.y = f2bf(o1);
    *(ushort2*)&obf[tid * 2] = ob;
    if (ofp) {
        float2 of; of.x = o0; of.y = o1;
        *(float2*)&ofp[tid * 2] = of;
    }
}

// ---------------------------------------------------------------------------
// scores[b,e,r] = sigmoid( sum_d relu(h_t[b,e,d] + h_i[b,r,d]) * W2[d] + b2 )
// One block per (b,e); wave w handles r = w, w+4, ...
// ---------------------------------------------------------------------------
__global__ __launch_bounds__(256) void scores_kernel(
    const float* __restrict__ ht, const float* __restrict__ hi,
    const float* __restrict__ W2, const float* __restrict__ b2,
    float* __restrict__ scores)
{
    const int be   = blockIdx.x;
    const int b    = be >> 6;
    const int tid  = threadIdx.x;
    const int lane = tid & 63;
    const int wave = tid >> 6;

    float htv[8], w2v[8];
    const float* htp = ht + (size_t)be * 512;
    #pragma unroll
    for (int j = 0; j < 8; ++j) {
        htv[j] = htp[lane + 64 * j];
        w2v[j] = W2[lane + 64 * j];
    }
    const float bb = b2[0];
    const float* hib = hi + (size_t)b * 36 * 512;

    for (int r = wave; r < 36; r += 4) {
        const float* hir = hib + (size_t)r * 512;
        float acc = 0.f;
        #pragma unroll
        for (int j = 0; j < 8; ++j) {
            float h = fmaxf(htv[j] + hir[lane + 64 * j], 0.f);
            acc = fmaf(h, w2v[j], acc);
        }
        #pragma unroll
        for (int off = 32; off; off >>= 1) acc += __shfl_down(acc, off);
        if (lane == 0) {
            float sr = acc + bb;
            scores[(size_t)be * 36 + r] = 1.f / (1.f + expf(-sr));
        }
    }
}

// ---------------------------------------------------------------------------
// Single-pass per-batch softmax + aggregation.
// partial[e4][r] over e = e4,e4+4,...  -> sexp[r] -> denom -> weighted sum.
// ---------------------------------------------------------------------------
__global__ __launch_bounds__(256) void agg_kernel(
    const float* __restrict__ scores, const float* __restrict__ img,
    float* __restrict__ outAgg)
{
    const int b   = blockIdx.x;
    const int tid = threadIdx.x;
    const float* sc = scores + (size_t)b * 2304;

    __shared__ float part[4][36];
    __shared__ float sexp[36];
    __shared__ float inv_s;

    const int e4 = tid >> 6;
    const int r  = tid & 63;
    if (r < 36) {
        float p = 0.f;
        #pragma unroll
        for (int e = 0; e < 16; ++e) p += expf(sc[(e * 4 + e4) * 36 + r]);
        part[e4][r] = p;
    }
    __syncthreads();
    if (tid < 36) sexp[tid] = part[0][tid] + part[1][tid] + part[2][tid] + part[3][tid];
    __syncthreads();
    if (tid < 64) {
        float v = (tid < 36) ? sexp[tid] : 0.f;
        #pragma unroll
        for (int off = 32; off; off >>= 1) v += __shfl_down(v, off);
        if (tid == 0) inv_s = 1.f / (v * 64.f);
    }
    __syncthreads();
    const float inv = inv_s;

    const float* ib = img + (size_t)b * 36 * 512;
    for (int d = tid; d < 512; d += 256) {
        float acc = 0.f;
        #pragma unroll
        for (int rr = 0; rr < 36; ++rr)
            acc = fmaf(sexp[rr] * inv, ib[rr * 512 + d], acc);
        outAgg[(size_t)b * 512 + d] = acc;
    }
}

// ---------------------------------------------------------------------------
extern "C" void kernel_launch(void* const* d_in, const int* in_sizes, int n_in,
                              void* d_out, int out_size, void* d_ws, size_t ws_size,
                              hipStream_t stream)
{
    const float* text      = (const float*)d_in[0];
    const float* image     = (const float*)d_in[1];
    const float* W_text    = (const float*)d_in[2];
    const float* b_text    = (const float*)d_in[3];
    const float* g_text    = (const float*)d_in[4];
    const float* beta_text = (const float*)d_in[5];
    const float* W_img     = (const float*)d_in[6];
    const float* b_img     = (const float*)d_in[7];
    const float* g_img     = (const float*)d_in[8];
    const float* beta_img  = (const float*)d_in[9];
    const float* W1        = (const float*)d_in[10];
    const float* b1        = (const float*)d_in[11];
    const float* W2        = (const float*)d_in[12];
    const float* b2        = (const float*)d_in[13];

    float* out_scores = (float*)d_out;            // 32*64*36
    float* out_agg    = (float*)d_out + 73728;    // 32*512

    char* ws = (char*)d_ws;
    float*    ta       = (float*)(ws);                          // 4 MB
    float*    ia       = (float*)(ws + (4u << 20));             // 2.25 MB
    ushort_t* text_bf  = (ushort_t*)(ws + 6402048);             // 3 MB   } region X
    ushort_t* image_bf = (ushort_t*)(ws + 6402048 + 3145728);   // 4.5 MB } 7.5 MB
    float*    ht       = (float*)(ws + 6402048);                // 4 MB   (aliases X)
    float*    hi       = (float*)(ws + 6402048 + 4194304);      // 2.25 MB(aliases X)
    char*     wbase    = ws + 6402048 + 7864320;
    ushort_t* Wt_t     = (ushort_t*)(wbase);                    // 0.75 MB
    ushort_t* Wi_t     = (ushort_t*)(wbase + 786432);           // 2 MB
    ushort_t* W1t_t    = (ushort_t*)(wbase + 786432 + 2097152); // 0.5 MB
    ushort_t* W1i_t    = (ushort_t*)(wbase + 786432 + 2097152 + 524288);
    char*     bfbase   = wbase + 786432 + 2097152 + 2 * 524288;
    ushort_t* ta_bf    = (ushort_t*)(bfbase);                   // 2 MB
    ushort_t* ia_bf    = (ushort_t*)(bfbase + 2097152);         // 1.125 MB

    // 1) convert activations + transpose weights (one launch)
    prep_kernel<<<5760, 256, 0, stream>>>(text, image, text_bf, image_bf,
                                          W_text, W_img, W1,
                                          Wt_t, Wi_t, W1t_t, W1i_t);
    // 2) both projections + bias + relu (one launch; y<32 text, else image)
    gemm_splitk_kernel<<<dim3(8, 50), 256, 0, stream>>>(
        text_bf, Wt_t, b_text, ta, 768,
        image_bf, Wi_t, b_img, ia, 2048,
        32, 1);
    // 3) both LayerNorms (one launch)
    ln_fused_kernel<<<3200, 256, 0, stream>>>(ta, g_text, beta_text, ta_bf,
                                              ia, g_img, beta_img, ia_bf);
    // 4) h_t (no bias) and h_i (+b1) (one launch)
    gemm_splitk_kernel<<<dim3(8, 50), 256, 0, stream>>>(
        ta_bf, W1t_t, nullptr, ht, 512,
        ia_bf, W1i_t, b1, hi, 512,
        32, 0);
    // 5) pair scores + sigmoid -> out[0]
    scores_kernel<<<2048, 256, 0, stream>>>(ht, hi, W2, b2, out_scores);
    // 6) softmax + aggregation -> out[1]
    agg_kernel<<<32, 256, 0, stream>>>(out_scores, ia, out_agg);
}